// Round 7
// baseline (494.857 us; speedup 1.0000x reference)
//
#include <hip/hip_runtime.h>

// BottleneckA fully fused: out = relu(W3·relu(g∘(W2·relu(g∘(W1·x+b1))+b2))+b3) + x
// x:[16,1024,56,56] f32, gate:[16,256], W1:[256,1024], W2:[256,256], W3:[1024,256]
//
// R7 = R3 design, resubmitted (7 failed rounds, all infra; zero counters all
// session). Rounds 3-6 spent on audit passes: swizzle bijectivity, bank-level
// access patterns, barrier/vmcnt coverage, VGPR budget, staging bounds, and
// numerics (precision profile identical to the harness-verified baseline:
// bf16 W/x-operand/h1/h2, f32 accum + epilogues).
//
// Structure: one block = one 64-pixel tile through all three layers.
//   Stage A: h1[64pix][256] = relu(g∘(W1·x+b1)) -> LDS (x f32 read, transposed
//            + bf16-converted in-flight; W1 staged via global_load_lds 16B;
//            x-loads software-pipelined one k-step ahead (T14)).
//   Stage B: h2 = relu(g∘(W2·h1+b2)) -> same LDS buffer (h1 dead after B).
//   Stage C: out = relu(W3·h2+b3) + x, 4 chunks of 256 out-channels.
// h1/h2 never touch HBM. LDS = 16KB Wstage + 32KB H + 4KB Xstage = 52KB
// -> 3 blocks/CU with __launch_bounds__(256,3) (k-loop live set ~130 VGPR < 168 cap).
// H buffer XOR-swizzled (byte ^= (pix&7)<<4): stride-512B k-operand b128 reads
// spread to 8 distinct 16B slots (+ free 2-way repeat) instead of 16-way.
// Grid 49x16 = 784 uniform blocks (NPIX = 49*64 exactly, no guards).
// HBM traffic: x 205MB (A) + xres 205MB + out 205MB (C) ≈ 620MB -> ~100µs floor.

#define NPIX 3136
#define BATCH 16

typedef __attribute__((ext_vector_type(8))) short short8;
typedef __attribute__((ext_vector_type(4))) float v4f;

__device__ __forceinline__ unsigned short f2bf(float f) {
    union { float f; unsigned u; } v; v.f = f;
    unsigned r = v.u + 0x7fffu + ((v.u >> 16) & 1u);
    return (unsigned short)(r >> 16);
}

__device__ __forceinline__ void ld_g2l16(const unsigned short* g, unsigned short* l) {
    __builtin_amdgcn_global_load_lds(
        (const __attribute__((address_space(1))) unsigned int*)g,
        (__attribute__((address_space(3))) unsigned int*)l,
        16, 0, 0);
}

// ---- W f32 -> bf16 (concatenated W1|W2|W3), 4 elems/thread ----
__global__ void convert_w(const float* __restrict__ W1, const float* __restrict__ W2,
                          const float* __restrict__ W3, unsigned short* __restrict__ Wb) {
    size_t e = ((size_t)blockIdx.x * 256 + threadIdx.x) * 4;
    const float* src; size_t off;
    if (e < 262144)      { src = W1; off = e; }
    else if (e < 327680) { src = W2; off = e - 262144; }
    else                 { src = W3; off = e - 327680; }
    float4 v = *reinterpret_cast<const float4*>(&src[off]);
    uint2 p;
    p.x = (unsigned)f2bf(v.x) | ((unsigned)f2bf(v.y) << 16);
    p.y = (unsigned)f2bf(v.z) | ((unsigned)f2bf(v.w) << 16);
    *reinterpret_cast<uint2*>(&Wb[e]) = p;
}

__global__ __launch_bounds__(256, 3) void moe_block(
    const float* __restrict__ x, const unsigned short* __restrict__ Wb,
    const float* __restrict__ b1, const float* __restrict__ b2,
    const float* __restrict__ b3, const float* __restrict__ gate,
    float* __restrict__ out)
{
    __shared__ __attribute__((aligned(16))) unsigned short Wsm[256 * 32]; // 16KB stage
    __shared__ __attribute__((aligned(16))) unsigned short Hsm[64 * 256]; // 32KB h1/h2
    __shared__ __attribute__((aligned(16))) unsigned short Xsm[64 * 32];  // 4KB x tile

    const unsigned short* W1b = Wb;
    const unsigned short* W2b = Wb + 262144;
    const unsigned short* W3b = Wb + 327680;

    const int b    = blockIdx.z;
    const int p0   = blockIdx.x * 64;
    const int t    = threadIdx.x;
    const int lane = t & 63;
    const int wave = t >> 6;
    const int wm   = wave * 64;
    const int l15  = lane & 15;
    const int quad = lane >> 4;

    const int srow  = t >> 2;        // 0..63 (W staging row)
    const int skoff = (t & 3) * 8;   // 16B k-offset

    char* hb = reinterpret_cast<char*>(Hsm);
    v4f acc[4][4];

    // ---------------- Stage A: h1 = relu(g ∘ (W1·x + b1)) ----------------
    #pragma unroll
    for (int i = 0; i < 4; ++i)
        #pragma unroll
        for (int j = 0; j < 4; ++j) acc[i][j] = (v4f){0.f, 0.f, 0.f, 0.f};

    {
        const unsigned short* wg = W1b + srow * 1024 + skoff;
        const int cp   = t & 15;     // channel pair: c = 2cp, 2cp+1
        const int pgrp = t >> 4;     // pixel group: 4 pix each
        const float* xg = x + ((size_t)(b * 1024 + 2 * cp)) * NPIX + p0 + pgrp * 4;
        unsigned* xw = reinterpret_cast<unsigned*>(&Xsm[pgrp * 128 + 2 * cp]);

        // prologue: prefetch k0=0
        float4 a0 = *reinterpret_cast<const float4*>(xg);
        float4 a1 = *reinterpret_cast<const float4*>(xg + NPIX);

        for (int k0 = 0; k0 < 1024; k0 += 32) {
            __syncthreads();
            ld_g2l16(wg + k0,          &Wsm[t * 8]);
            ld_g2l16(wg + k0 + 65536,  &Wsm[2048 + t * 8]);
            ld_g2l16(wg + k0 + 131072, &Wsm[4096 + t * 8]);
            ld_g2l16(wg + k0 + 196608, &Wsm[6144 + t * 8]);
            unsigned u0 = (unsigned)f2bf(a0.x) | ((unsigned)f2bf(a1.x) << 16);
            unsigned u1 = (unsigned)f2bf(a0.y) | ((unsigned)f2bf(a1.y) << 16);
            unsigned u2 = (unsigned)f2bf(a0.z) | ((unsigned)f2bf(a1.z) << 16);
            unsigned u3 = (unsigned)f2bf(a0.w) | ((unsigned)f2bf(a1.w) << 16);
            xw[0] = u0; xw[16] = u1; xw[32] = u2; xw[48] = u3;
            __syncthreads();

            // T14: issue next k-step's x loads; in flight during MFMA phase,
            // drained at the next loop-top barrier.
            if (k0 + 32 < 1024) {
                const float* xp = xg + (size_t)(k0 + 32) * NPIX;
                a0 = *reinterpret_cast<const float4*>(xp);
                a1 = *reinterpret_cast<const float4*>(xp + NPIX);
            }

            short8 rf[4], cf[4];
            #pragma unroll
            for (int mt = 0; mt < 4; ++mt)
                rf[mt] = *reinterpret_cast<const short8*>(
                    &Wsm[(wm + mt * 16 + l15) * 32 + quad * 8]);
            #pragma unroll
            for (int nt = 0; nt < 4; ++nt)
                cf[nt] = *reinterpret_cast<const short8*>(
                    &Xsm[(nt * 16 + l15) * 32 + quad * 8]);
            #pragma unroll
            for (int mt = 0; mt < 4; ++mt)
                #pragma unroll
                for (int nt = 0; nt < 4; ++nt)
                    acc[mt][nt] = __builtin_amdgcn_mfma_f32_16x16x32_bf16(
                        rf[mt], cf[nt], acc[mt][nt], 0, 0, 0);
        }
    }

    // epilogue A -> Hsm[pix][o1], swizzled
    #pragma unroll
    for (int mt = 0; mt < 4; ++mt) {
        const int o = wm + mt * 16 + quad * 4;
        const float4 bi = *reinterpret_cast<const float4*>(&b1[o]);
        const float4 gv = *reinterpret_cast<const float4*>(&gate[b * 256 + o]);
        const float g0 = gv.x > 0.f ? gv.x : 0.f;
        const float g1 = gv.y > 0.f ? gv.y : 0.f;
        const float g2 = gv.z > 0.f ? gv.z : 0.f;
        const float g3 = gv.w > 0.f ? gv.w : 0.f;
        #pragma unroll
        for (int nt = 0; nt < 4; ++nt) {
            const int pix = nt * 16 + l15;
            float v0 = (acc[mt][nt][0] + bi.x) * g0;
            float v1 = (acc[mt][nt][1] + bi.y) * g1;
            float v2 = (acc[mt][nt][2] + bi.z) * g2;
            float v3 = (acc[mt][nt][3] + bi.w) * g3;
            v0 = v0 > 0.f ? v0 : 0.f; v1 = v1 > 0.f ? v1 : 0.f;
            v2 = v2 > 0.f ? v2 : 0.f; v3 = v3 > 0.f ? v3 : 0.f;
            uint2 pq;
            pq.x = (unsigned)f2bf(v0) | ((unsigned)f2bf(v1) << 16);
            pq.y = (unsigned)f2bf(v2) | ((unsigned)f2bf(v3) << 16);
            const unsigned off = (unsigned)(pix * 512 + o * 2) ^ (unsigned)((pix & 7) << 4);
            *reinterpret_cast<uint2*>(hb + off) = pq;
        }
    }

    // ---------------- Stage B: h2 = relu(g ∘ (W2·h1 + b2)) ----------------
    #pragma unroll
    for (int i = 0; i < 4; ++i)
        #pragma unroll
        for (int j = 0; j < 4; ++j) acc[i][j] = (v4f){0.f, 0.f, 0.f, 0.f};

    {
        const unsigned short* wg = W2b + srow * 256 + skoff;
        for (int k0 = 0; k0 < 256; k0 += 32) {
            __syncthreads();   // also covers: epilogue-A writes visible, Wsm free
            ld_g2l16(wg + k0,         &Wsm[t * 8]);
            ld_g2l16(wg + k0 + 16384, &Wsm[2048 + t * 8]);
            ld_g2l16(wg + k0 + 32768, &Wsm[4096 + t * 8]);
            ld_g2l16(wg + k0 + 49152, &Wsm[6144 + t * 8]);
            __syncthreads();

            short8 rf[4], cf[4];
            #pragma unroll
            for (int mt = 0; mt < 4; ++mt)
                rf[mt] = *reinterpret_cast<const short8*>(
                    &Wsm[(wm + mt * 16 + l15) * 32 + quad * 8]);
            #pragma unroll
            for (int nt = 0; nt < 4; ++nt) {
                const int row = nt * 16 + l15;
                const unsigned off =
                    (unsigned)(row * 512 + k0 * 2 + quad * 16) ^ (unsigned)((row & 7) << 4);
                cf[nt] = *reinterpret_cast<const short8*>(hb + off);
            }
            #pragma unroll
            for (int mt = 0; mt < 4; ++mt)
                #pragma unroll
                for (int nt = 0; nt < 4; ++nt)
                    acc[mt][nt] = __builtin_amdgcn_mfma_f32_16x16x32_bf16(
                        rf[mt], cf[nt], acc[mt][nt], 0, 0, 0);
        }
    }

    __syncthreads();  // all h1 reads done before h2 overwrites Hsm

    // epilogue B -> Hsm[pix][o2], swizzled (overwrites h1)
    #pragma unroll
    for (int mt = 0; mt < 4; ++mt) {
        const int o = wm + mt * 16 + quad * 4;
        const float4 bi = *reinterpret_cast<const float4*>(&b2[o]);
        const float4 gv = *reinterpret_cast<const float4*>(&gate[b * 256 + o]);
        const float g0 = gv.x > 0.f ? gv.x : 0.f;
        const float g1 = gv.y > 0.f ? gv.y : 0.f;
        const float g2 = gv.z > 0.f ? gv.z : 0.f;
        const float g3 = gv.w > 0.f ? gv.w : 0.f;
        #pragma unroll
        for (int nt = 0; nt < 4; ++nt) {
            const int pix = nt * 16 + l15;
            float v0 = (acc[mt][nt][0] + bi.x) * g0;
            float v1 = (acc[mt][nt][1] + bi.y) * g1;
            float v2 = (acc[mt][nt][2] + bi.z) * g2;
            float v3 = (acc[mt][nt][3] + bi.w) * g3;
            v0 = v0 > 0.f ? v0 : 0.f; v1 = v1 > 0.f ? v1 : 0.f;
            v2 = v2 > 0.f ? v2 : 0.f; v3 = v3 > 0.f ? v3 : 0.f;
            uint2 pq;
            pq.x = (unsigned)f2bf(v0) | ((unsigned)f2bf(v1) << 16);
            pq.y = (unsigned)f2bf(v2) | ((unsigned)f2bf(v3) << 16);
            const unsigned off = (unsigned)(pix * 512 + o * 2) ^ (unsigned)((pix & 7) << 4);
            *reinterpret_cast<uint2*>(hb + off) = pq;
        }
    }

    // ---------------- Stage C: out = relu(W3·h2 + b3) + x ----------------
    for (int ch = 0; ch < 4; ++ch) {
        const int oc0 = ch * 256;
        const unsigned short* wg = W3b + (size_t)(oc0 + srow) * 256 + skoff;

        #pragma unroll
        for (int i = 0; i < 4; ++i)
            #pragma unroll
            for (int j = 0; j < 4; ++j) acc[i][j] = (v4f){0.f, 0.f, 0.f, 0.f};

        for (int k0 = 0; k0 < 256; k0 += 32) {
            __syncthreads();  // covers epilogue-B visibility / Wsm reuse
            ld_g2l16(wg + k0,         &Wsm[t * 8]);
            ld_g2l16(wg + k0 + 16384, &Wsm[2048 + t * 8]);
            ld_g2l16(wg + k0 + 32768, &Wsm[4096 + t * 8]);
            ld_g2l16(wg + k0 + 49152, &Wsm[6144 + t * 8]);
            __syncthreads();

            short8 rf[4], cf[4];
            #pragma unroll
            for (int mt = 0; mt < 4; ++mt) {       // rows = pix from Hsm (h2)
                const int row = mt * 16 + l15;
                const unsigned off =
                    (unsigned)(row * 512 + k0 * 2 + quad * 16) ^ (unsigned)((row & 7) << 4);
                rf[mt] = *reinterpret_cast<const short8*>(hb + off);
            }
            #pragma unroll
            for (int nt = 0; nt < 4; ++nt)         // cols = o3 from Wsm
                cf[nt] = *reinterpret_cast<const short8*>(
                    &Wsm[(wm + nt * 16 + l15) * 32 + quad * 8]);
            #pragma unroll
            for (int mt = 0; mt < 4; ++mt)
                #pragma unroll
                for (int nt = 0; nt < 4; ++nt)
                    acc[mt][nt] = __builtin_amdgcn_mfma_f32_16x16x32_bf16(
                        rf[mt], cf[nt], acc[mt][nt], 0, 0, 0);
        }

        // chunk epilogue: relu + bias + residual, f32 out [b][o][pix]
        #pragma unroll
        for (int nt = 0; nt < 4; ++nt) {
            const int o = oc0 + wm + nt * 16 + l15;
            const float bi = b3[o];
            #pragma unroll
            for (int mt = 0; mt < 4; ++mt) {
                const int pix = p0 + mt * 16 + quad * 4;
                const size_t base = ((size_t)(b * 1024 + o)) * NPIX + pix;
                const float4 xr = *reinterpret_cast<const float4*>(&x[base]);
                float v0 = acc[mt][nt][0] + bi, v1 = acc[mt][nt][1] + bi;
                float v2 = acc[mt][nt][2] + bi, v3 = acc[mt][nt][3] + bi;
                float4 ov;
                ov.x = (v0 > 0.f ? v0 : 0.f) + xr.x;
                ov.y = (v1 > 0.f ? v1 : 0.f) + xr.y;
                ov.z = (v2 > 0.f ? v2 : 0.f) + xr.z;
                ov.w = (v3 > 0.f ? v3 : 0.f) + xr.w;
                *reinterpret_cast<float4*>(&out[base]) = ov;
            }
        }
    }
}

extern "C" void kernel_launch(void* const* d_in, const int* in_sizes, int n_in,
                              void* d_out, int out_size, void* d_ws, size_t ws_size,
                              hipStream_t stream) {
    const float* x    = (const float*)d_in[0];
    const float* gate = (const float*)d_in[1];
    const float* W1   = (const float*)d_in[2];
    const float* b1   = (const float*)d_in[3];
    const float* W2   = (const float*)d_in[4];
    const float* b2   = (const float*)d_in[5];
    const float* W3   = (const float*)d_in[6];
    const float* b3   = (const float*)d_in[7];
    float* out = (float*)d_out;

    unsigned short* Wb = (unsigned short*)d_ws;   // 589824 ushorts ≈ 1.18 MB

    dim3 blk(256);
    convert_w<<<576, blk, 0, stream>>>(W1, W2, W3, Wb);
    moe_block<<<dim3(49, 1, BATCH), blk, 0, stream>>>(x, Wb, b1, b2, b3, gate, out);
}